// Round 1
// baseline (338.060 us; speedup 1.0000x reference)
//
#include <hip/hip_runtime.h>

// Problem: N=4096, A=512, C=100 (derived from in_sizes at launch).
// Outputs flat: [loss(1), new_cov(C*A*A), new_ave(C*A), new_amount(C)]

#define TILE 64
#define KC 16

__global__ void init_kernel(int* counts, int* cursors, float* loss_acc, int C) {
    int t = blockIdx.x * blockDim.x + threadIdx.x;
    if (t < C) { counts[t] = 0; cursors[t] = 0; }
    if (t == 0) *loss_acc = 0.f;
}

__global__ void count_kernel(const int* __restrict__ labels, int* __restrict__ counts, int N) {
    int n = blockIdx.x * blockDim.x + threadIdx.x;
    if (n < N) atomicAdd(&counts[labels[n]], 1);
}

// single block: per-class scalars + serial prefix sum (C is tiny)
__global__ void scan_kernel(const int* __restrict__ counts, const float* __restrict__ Amount,
                            int* __restrict__ offsets, float* __restrict__ w_arr,
                            float* __restrict__ inv_cs, float* __restrict__ amount_out, int C) {
    for (int c = threadIdx.x; c < C; c += blockDim.x) {
        float cf = (float)counts[c];
        float cs = cf > 0.f ? cf : 1.f;          // counts_safe
        inv_cs[c] = 1.f / cs;
        float am = Amount[c];
        float denom = cf + am;
        w_arr[c] = denom > 0.f ? cf / denom : 0.f;
        amount_out[c] = am + cf;                  // new_amount
    }
    if (threadIdx.x == 0) {
        int off = 0;
        for (int i = 0; i < C; ++i) { offsets[i] = off; off += counts[i]; }
        offsets[C] = off;
    }
}

__global__ void scatter_kernel(const int* __restrict__ labels, const int* __restrict__ offsets,
                               int* __restrict__ cursors, int* __restrict__ idx_sorted, int N) {
    int n = blockIdx.x * blockDim.x + threadIdx.x;
    if (n < N) {
        int c = labels[n];
        int pos = atomicAdd(&cursors[c], 1);
        idx_sorted[offsets[c] + pos] = n;
    }
}

// block per class, A threads: per-class mean + fused new_ave output
__global__ void ave_kernel(const float* __restrict__ feats, const float* __restrict__ Ave_in,
                           const int* __restrict__ idx_sorted, const int* __restrict__ offsets,
                           const float* __restrict__ w_arr, const float* __restrict__ inv_cs,
                           float* __restrict__ ave_new, float* __restrict__ ave_out, int A) {
    int c = blockIdx.x;
    int a = threadIdx.x;
    int base = offsets[c];
    int nc = offsets[c + 1] - base;
    float s = 0.f;
    for (int i = 0; i < nc; ++i) {
        int row = idx_sorted[base + i];
        s += feats[(size_t)row * A + a];
    }
    float av = s * inv_cs[c];
    ave_new[(size_t)c * A + a] = av;
    float w = w_arr[c];
    ave_out[(size_t)c * A + a] = Ave_in[(size_t)c * A + a] * (1.f - w) + av * w;
}

// block = (class c, 64x64 tile of A x A). Fused epilogue writes new_cov.
__global__ __launch_bounds__(256) void cov_kernel(
    const float* __restrict__ feats, const float* __restrict__ cov_in,
    const float* __restrict__ Ave_in, const float* __restrict__ ave_new,
    const int* __restrict__ idx_sorted, const int* __restrict__ offsets,
    const float* __restrict__ w_arr, const float* __restrict__ inv_cs,
    float* __restrict__ cov_out, int A) {
    const int c = blockIdx.z;
    const int a0 = blockIdx.y * TILE;
    const int b0 = blockIdx.x * TILE;
    const int tid = threadIdx.x;

    __shared__ float Xa[KC][TILE];
    __shared__ float Xb[KC][TILE];
    __shared__ float aveA[TILE], aveB[TILE], dA[TILE], dB[TILE];

    if (tid < TILE) {
        float av = ave_new[(size_t)c * A + a0 + tid];
        aveA[tid] = av;
        dA[tid] = Ave_in[(size_t)c * A + a0 + tid] - av;
    } else if (tid < 2 * TILE) {
        int t = tid - TILE;
        float bv = ave_new[(size_t)c * A + b0 + t];
        aveB[t] = bv;
        dB[t] = Ave_in[(size_t)c * A + b0 + t] - bv;
    }

    const int base = offsets[c];
    const int nc = offsets[c + 1] - base;
    const int ty = tid >> 4, tx = tid & 15;

    float acc[4][4] = {};

    // staging assignment: each thread loads one float4 per slice per chunk
    const int li = tid >> 4;          // member within chunk (0..15)
    const int lcg = (tid & 15) * 4;   // column group (0,4,...,60)

    for (int kk = 0; kk < nc; kk += KC) {
        const int kn = min(KC, nc - kk);
        __syncthreads();  // protect previous iteration's reads (and first-iter ave preload)
        float4 va = make_float4(0.f, 0.f, 0.f, 0.f);
        float4 vb = va;
        if (li < kn) {
            int row = idx_sorted[base + kk + li];
            const float* fr = feats + (size_t)row * A;
            va = *reinterpret_cast<const float4*>(fr + a0 + lcg);
            vb = *reinterpret_cast<const float4*>(fr + b0 + lcg);
            va.x -= aveA[lcg]; va.y -= aveA[lcg + 1]; va.z -= aveA[lcg + 2]; va.w -= aveA[lcg + 3];
            vb.x -= aveB[lcg]; vb.y -= aveB[lcg + 1]; vb.z -= aveB[lcg + 2]; vb.w -= aveB[lcg + 3];
        }
        *reinterpret_cast<float4*>(&Xa[li][lcg]) = va;
        *reinterpret_cast<float4*>(&Xb[li][lcg]) = vb;
        __syncthreads();

        #pragma unroll
        for (int k = 0; k < KC; ++k) {   // tail rows are zeroed -> safe to run full KC
            float4 av4 = *reinterpret_cast<const float4*>(&Xa[k][ty * 4]);
            float4 bv4 = *reinterpret_cast<const float4*>(&Xb[k][tx * 4]);
            float a4[4] = {av4.x, av4.y, av4.z, av4.w};
            float b4[4] = {bv4.x, bv4.y, bv4.z, bv4.w};
            #pragma unroll
            for (int i = 0; i < 4; ++i)
                #pragma unroll
                for (int j = 0; j < 4; ++j)
                    acc[i][j] += a4[i] * b4[j];
        }
    }
    __syncthreads();  // ensure dA/dB visible even when nc==0

    const float w = w_arr[c];
    const float omw = 1.f - w;
    const float aw = w * omw;
    const float s = inv_cs[c] * w;   // var_temp*w = acc * (inv_counts_safe * w)
    const size_t cbase = (size_t)c * A * A;
    float db[4] = {dB[tx * 4], dB[tx * 4 + 1], dB[tx * 4 + 2], dB[tx * 4 + 3]};

    #pragma unroll
    for (int i = 0; i < 4; ++i) {
        int r = a0 + ty * 4 + i;
        size_t o = cbase + (size_t)r * A + b0 + tx * 4;
        float4 co = *reinterpret_cast<const float4*>(&cov_in[o]);
        float da = dA[ty * 4 + i];
        float4 res;
        res.x = co.x * omw + acc[i][0] * s + aw * da * db[0];
        res.y = co.y * omw + acc[i][1] * s + aw * da * db[1];
        res.z = co.z * omw + acc[i][2] * s + aw * da * db[2];
        res.w = co.w * omw + acc[i][3] * s + aw * da * db[3];
        *reinterpret_cast<float4*>(&cov_out[o]) = res;
    }
}

// one wave (64 lanes) per row of y_s
__global__ void loss_kernel(const float* __restrict__ y_s, const int* __restrict__ labels,
                            float* __restrict__ loss_acc, int N, int C) {
    int wv = (blockIdx.x * blockDim.x + threadIdx.x) >> 6;
    int lane = threadIdx.x & 63;
    if (wv >= N) return;
    const float* row = y_s + (size_t)wv * C;
    float m = -1e30f;
    for (int col = lane; col < C; col += 64) m = fmaxf(m, row[col]);
    #pragma unroll
    for (int off = 32; off > 0; off >>= 1) m = fmaxf(m, __shfl_xor(m, off));
    float se = 0.f;
    for (int col = lane; col < C; col += 64) se += expf(row[col] - m);
    #pragma unroll
    for (int off = 32; off > 0; off >>= 1) se += __shfl_xor(se, off);
    if (lane == 0) {
        float yt = row[labels[wv]];
        float l = -(yt - m - logf(se));
        atomicAdd(loss_acc, l);
    }
}

__global__ void finalize_kernel(const float* __restrict__ loss_acc, float* __restrict__ out_loss,
                                float invN) {
    if (threadIdx.x == 0 && blockIdx.x == 0) out_loss[0] = loss_acc[0] * invN;
}

extern "C" void kernel_launch(void* const* d_in, const int* in_sizes, int n_in,
                              void* d_out, int out_size, void* d_ws, size_t ws_size,
                              hipStream_t stream) {
    const float* feats  = (const float*)d_in[0];
    const float* y_s    = (const float*)d_in[1];
    const float* cov_in = (const float*)d_in[2];
    const float* Ave_in = (const float*)d_in[3];
    const float* Amount = (const float*)d_in[4];
    const int*   labels = (const int*)d_in[5];

    const int C = in_sizes[4];
    const int N = in_sizes[5];
    const int A = in_sizes[3] / C;

    float* out      = (float*)d_out;
    float* out_loss = out;
    float* out_cov  = out + 1;
    float* out_ave  = out_cov + (size_t)C * A * A;
    float* out_amt  = out_ave + (size_t)C * A;

    // workspace layout
    char* w8 = (char*)d_ws;
    int* counts     = (int*)w8;   w8 += (size_t)C * sizeof(int);
    int* cursors    = (int*)w8;   w8 += (size_t)C * sizeof(int);
    int* offsets    = (int*)w8;   w8 += (size_t)(C + 1) * sizeof(int);
    int* idx_sorted = (int*)w8;   w8 += (size_t)N * sizeof(int);
    float* loss_acc = (float*)w8; w8 += sizeof(float);
    float* w_arr    = (float*)w8; w8 += (size_t)C * sizeof(float);
    float* inv_cs   = (float*)w8; w8 += (size_t)C * sizeof(float);
    float* ave_new  = (float*)w8; w8 += (size_t)C * A * sizeof(float);

    init_kernel<<<(C + 255) / 256, 256, 0, stream>>>(counts, cursors, loss_acc, C);
    count_kernel<<<(N + 255) / 256, 256, 0, stream>>>(labels, counts, N);
    scan_kernel<<<1, 128, 0, stream>>>(counts, Amount, offsets, w_arr, inv_cs, out_amt, C);
    scatter_kernel<<<(N + 255) / 256, 256, 0, stream>>>(labels, offsets, cursors, idx_sorted, N);
    ave_kernel<<<C, A, 0, stream>>>(feats, Ave_in, idx_sorted, offsets, w_arr, inv_cs,
                                    ave_new, out_ave, A);
    dim3 grid(A / TILE, A / TILE, C);
    cov_kernel<<<grid, 256, 0, stream>>>(feats, cov_in, Ave_in, ave_new, idx_sorted, offsets,
                                         w_arr, inv_cs, out_cov, A);
    loss_kernel<<<(N * 64 + 255) / 256, 256, 0, stream>>>(y_s, labels, loss_acc, N, C);
    finalize_kernel<<<1, 64, 0, stream>>>(loss_acc, out_loss, 1.f / (float)N);
}

// Round 2
// 263.555 us; speedup vs baseline: 1.2827x; 1.2827x over previous
//
#include <hip/hip_runtime.h>

// N=4096, A=512, C=100 (derived at launch).
// Outputs flat: [loss(1), new_cov(C*A*A), new_ave(C*A), new_amount(C)]

#define TM 128          // cov block tile (TM x TM)
#define KC 16           // k-chunk rows staged in LDS
#define LSTR 132        // padded LDS row stride (floats); 132*4B % 16B == 0, breaks 8-way write conflicts

// ---------------- fused prep: histogram + scan + per-class scalars ----------------
__global__ void fused_prep(const int* __restrict__ labels, const float* __restrict__ Amount,
                           int* __restrict__ offsets, int* __restrict__ cursors,
                           float* __restrict__ w_arr, float* __restrict__ inv_cs,
                           float* __restrict__ amount_out, float* __restrict__ loss_acc,
                           int N, int C) {
    __shared__ int hist[1024];
    __shared__ int offs[1025];
    int tid = threadIdx.x;
    for (int c = tid; c < C; c += blockDim.x) hist[c] = 0;
    __syncthreads();
    for (int i = tid; i < N; i += blockDim.x) atomicAdd(&hist[labels[i]], 1);
    __syncthreads();
    if (tid == 0) {
        int o = 0;
        for (int c = 0; c < C; ++c) { offs[c] = o; o += hist[c]; }
        offs[C] = o;
    }
    __syncthreads();
    for (int c = tid; c < C; c += blockDim.x) {
        float cf = (float)hist[c];
        float cs = cf > 0.f ? cf : 1.f;
        inv_cs[c] = 1.f / cs;
        float am = Amount[c];
        float dn = cf + am;
        w_arr[c] = dn > 0.f ? cf / dn : 0.f;
        amount_out[c] = am + cf;
        offsets[c] = offs[c];
        cursors[c] = 0;
    }
    if (tid == 0) { offsets[C] = offs[C]; loss_acc[0] = 0.f; }
}

__global__ void scatter_kernel(const int* __restrict__ labels, const int* __restrict__ offsets,
                               int* __restrict__ cursors, int* __restrict__ idx_sorted, int N) {
    int n = blockIdx.x * blockDim.x + threadIdx.x;
    if (n < N) {
        int c = labels[n];
        int pos = atomicAdd(&cursors[c], 1);
        idx_sorted[offsets[c] + pos] = n;
    }
}

// ---------------- per-class mean + fused new_ave; grid (A/128, C), 128 threads ----------------
__global__ __launch_bounds__(128) void ave_kernel(
    const float* __restrict__ feats, const float* __restrict__ Ave_in,
    const int* __restrict__ idx_sorted, const int* __restrict__ offsets,
    const float* __restrict__ w_arr, const float* __restrict__ inv_cs,
    float* __restrict__ ave_new, float* __restrict__ ave_out, int A) {
    __shared__ int idxs[512];
    const int c = blockIdx.y;
    const int col = blockIdx.x * 128 + threadIdx.x;
    const int base = offsets[c];
    const int nc = offsets[c + 1] - base;
    float sum = 0.f;
    for (int i0 = 0; i0 < nc; i0 += 512) {
        int chunk = min(512, nc - i0);
        __syncthreads();
        for (int j = threadIdx.x; j < chunk; j += 128) idxs[j] = idx_sorted[base + i0 + j];
        __syncthreads();
        int j = 0;
        for (; j + 3 < chunk; j += 4) {
            int r0 = idxs[j], r1 = idxs[j + 1], r2 = idxs[j + 2], r3 = idxs[j + 3];
            float f0 = feats[(size_t)r0 * A + col];
            float f1 = feats[(size_t)r1 * A + col];
            float f2 = feats[(size_t)r2 * A + col];
            float f3 = feats[(size_t)r3 * A + col];
            sum += f0 + f1 + f2 + f3;
        }
        for (; j < chunk; ++j) sum += feats[(size_t)idxs[j] * A + col];
    }
    float av = sum * inv_cs[c];
    ave_new[(size_t)c * A + col] = av;
    float w = w_arr[c];
    ave_out[(size_t)c * A + col] = Ave_in[(size_t)c * A + col] * (1.f - w) + av * w;
}

// ---------------- cov: block = (class, 128x128 tile), 256 threads, 8x8 acc/thread ----------------
__global__ __launch_bounds__(256) void cov_kernel(
    const float* __restrict__ feats, const float* __restrict__ cov_in,
    const float* __restrict__ ave_new, const float* __restrict__ Ave_in,
    const int* __restrict__ idx_sorted, const int* __restrict__ offsets,
    const float* __restrict__ w_arr, const float* __restrict__ inv_cs,
    float* __restrict__ cov_out, int A) {
    const int c  = blockIdx.z;
    const int a0 = blockIdx.y * TM;
    const int b0 = blockIdx.x * TM;
    const int tid = threadIdx.x;
    const int ty = tid >> 4, tx = tid & 15;

    __shared__ float Xa[KC][LSTR];
    __shared__ float Xb[KC][LSTR];
    __shared__ float aveA[TM], aveB[TM], dA[TM], dB[TM];

    // preload class means + (old - new) diffs for this tile's rows/cols
    if (tid < TM) {
        float av = ave_new[(size_t)c * A + a0 + tid];
        aveA[tid] = av;
        dA[tid] = Ave_in[(size_t)c * A + a0 + tid] - av;
    } else {
        int t = tid - TM;
        float bv = ave_new[(size_t)c * A + b0 + t];
        aveB[t] = bv;
        dB[t] = Ave_in[(size_t)c * A + b0 + t] - bv;
    }

    const float w   = w_arr[c];          // uniform per block
    const float omw = 1.f - w;
    const float s   = inv_cs[c] * w;     // var_temp scale * w
    const float aw  = w * omw;
    const size_t cbase = (size_t)c * A * A;

    float acc[2][4][2][4] = {};          // [ri][i][ci][j]

    if (s > 0.f) {
        // fold cov_in*(1-w) into acc init so the read overlaps the k-loop.
        // runtime skip when (1-w)==0: contribution is exactly 0 (generic for finite inputs).
        if (omw != 0.f) {
            const float sc = omw / s;
            #pragma unroll
            for (int ri = 0; ri < 2; ++ri)
                #pragma unroll
                for (int i = 0; i < 4; ++i) {
                    const size_t rowo = cbase + (size_t)(a0 + ri * 64 + ty * 4 + i) * A + b0;
                    #pragma unroll
                    for (int ci = 0; ci < 2; ++ci) {
                        float4 co = *reinterpret_cast<const float4*>(&cov_in[rowo + ci * 64 + tx * 4]);
                        acc[ri][i][ci][0] = co.x * sc;
                        acc[ri][i][ci][1] = co.y * sc;
                        acc[ri][i][ci][2] = co.z * sc;
                        acc[ri][i][ci][3] = co.w * sc;
                    }
                }
        }

        const int base = offsets[c];
        const int nc = offsets[c + 1] - base;
        const int li = ty;            // staging row in chunk (0..15)
        const int cg = tx * 4;        // staging col group

        __syncthreads();              // aveA/aveB ready

        for (int kk = 0; kk < nc; kk += KC) {
            const int kn = min(KC, nc - kk);
            float4 va0 = make_float4(0.f, 0.f, 0.f, 0.f), va1 = va0, vb0 = va0, vb1 = va0;
            if (li < kn) {
                int row = idx_sorted[base + kk + li];
                const float* fr = feats + (size_t)row * A;
                va0 = *reinterpret_cast<const float4*>(fr + a0 + cg);
                va1 = *reinterpret_cast<const float4*>(fr + a0 + cg + 64);
                vb0 = *reinterpret_cast<const float4*>(fr + b0 + cg);
                vb1 = *reinterpret_cast<const float4*>(fr + b0 + cg + 64);
                va0.x -= aveA[cg];      va0.y -= aveA[cg + 1];      va0.z -= aveA[cg + 2];      va0.w -= aveA[cg + 3];
                va1.x -= aveA[cg + 64]; va1.y -= aveA[cg + 65];     va1.z -= aveA[cg + 66];     va1.w -= aveA[cg + 67];
                vb0.x -= aveB[cg];      vb0.y -= aveB[cg + 1];      vb0.z -= aveB[cg + 2];      vb0.w -= aveB[cg + 3];
                vb1.x -= aveB[cg + 64]; vb1.y -= aveB[cg + 65];     vb1.z -= aveB[cg + 66];     vb1.w -= aveB[cg + 67];
            }
            __syncthreads();          // protect previous chunk's fragment reads
            *reinterpret_cast<float4*>(&Xa[li][cg])      = va0;
            *reinterpret_cast<float4*>(&Xa[li][cg + 64]) = va1;
            *reinterpret_cast<float4*>(&Xb[li][cg])      = vb0;
            *reinterpret_cast<float4*>(&Xb[li][cg + 64]) = vb1;
            __syncthreads();

            #pragma unroll
            for (int k = 0; k < KC; ++k) {   // zero-padded tail rows are safe
                float4 a0v = *reinterpret_cast<const float4*>(&Xa[k][ty * 4]);
                float4 a1v = *reinterpret_cast<const float4*>(&Xa[k][64 + ty * 4]);
                float4 b0v = *reinterpret_cast<const float4*>(&Xb[k][tx * 4]);
                float4 b1v = *reinterpret_cast<const float4*>(&Xb[k][64 + tx * 4]);
                float af[2][4] = {{a0v.x, a0v.y, a0v.z, a0v.w}, {a1v.x, a1v.y, a1v.z, a1v.w}};
                float bf[2][4] = {{b0v.x, b0v.y, b0v.z, b0v.w}, {b1v.x, b1v.y, b1v.z, b1v.w}};
                #pragma unroll
                for (int ri = 0; ri < 2; ++ri)
                    #pragma unroll
                    for (int i = 0; i < 4; ++i)
                        #pragma unroll
                        for (int ci = 0; ci < 2; ++ci)
                            #pragma unroll
                            for (int j = 0; j < 4; ++j)
                                acc[ri][i][ci][j] += af[ri][i] * bf[ci][j];
            }
        }

        // epilogue: out = acc*s + w(1-w)*dA*dB   (cov_in already folded in)
        float db[2][4];
        #pragma unroll
        for (int ci = 0; ci < 2; ++ci)
            #pragma unroll
            for (int j = 0; j < 4; ++j) db[ci][j] = dB[ci * 64 + tx * 4 + j];

        #pragma unroll
        for (int ri = 0; ri < 2; ++ri)
            #pragma unroll
            for (int i = 0; i < 4; ++i) {
                float da = dA[ri * 64 + ty * 4 + i];
                const size_t rowo = cbase + (size_t)(a0 + ri * 64 + ty * 4 + i) * A + b0;
                #pragma unroll
                for (int ci = 0; ci < 2; ++ci) {
                    float4 res;
                    res.x = acc[ri][i][ci][0] * s + aw * da * db[ci][0];
                    res.y = acc[ri][i][ci][1] * s + aw * da * db[ci][1];
                    res.z = acc[ri][i][ci][2] * s + aw * da * db[ci][2];
                    res.w = acc[ri][i][ci][3] * s + aw * da * db[ci][3];
                    *reinterpret_cast<float4*>(&cov_out[rowo + ci * 64 + tx * 4]) = res;
                }
            }
    } else {
        // w == 0: new_cov = cov_in * (1-w); var and diff terms vanish
        #pragma unroll
        for (int ri = 0; ri < 2; ++ri)
            #pragma unroll
            for (int i = 0; i < 4; ++i) {
                const size_t rowo = cbase + (size_t)(a0 + ri * 64 + ty * 4 + i) * A + b0;
                #pragma unroll
                for (int ci = 0; ci < 2; ++ci) {
                    float4 co = *reinterpret_cast<const float4*>(&cov_in[rowo + ci * 64 + tx * 4]);
                    float4 res = make_float4(co.x * omw, co.y * omw, co.z * omw, co.w * omw);
                    *reinterpret_cast<float4*>(&cov_out[rowo + ci * 64 + tx * 4]) = res;
                }
            }
    }
}

// ---------------- loss: 64 blocks, one wave handles 16 rows, block-reduced atomic ----------------
__global__ __launch_bounds__(256) void loss_kernel(
    const float* __restrict__ y_s, const int* __restrict__ labels,
    float* __restrict__ loss_acc, int N, int C) {
    __shared__ float bsum[4];
    const int lane = threadIdx.x & 63;
    const int wv = threadIdx.x >> 6;                         // wave in block (0..3)
    const int gw = blockIdx.x * 4 + wv;                      // global wave id
    const int nwaves = gridDim.x * 4;
    float wsum = 0.f;
    for (int r = gw; r < N; r += nwaves) {
        const float* row = y_s + (size_t)r * C;
        float m = -1e30f;
        for (int col = lane; col < C; col += 64) m = fmaxf(m, row[col]);
        #pragma unroll
        for (int off = 32; off > 0; off >>= 1) m = fmaxf(m, __shfl_xor(m, off));
        float se = 0.f;
        for (int col = lane; col < C; col += 64) se += __expf(row[col] - m);
        #pragma unroll
        for (int off = 32; off > 0; off >>= 1) se += __shfl_xor(se, off);
        if (lane == 0) wsum += -(row[labels[r]] - m - __logf(se));
    }
    if (lane == 0) bsum[wv] = wsum;
    __syncthreads();
    if (threadIdx.x == 0) {
        float t = bsum[0] + bsum[1] + bsum[2] + bsum[3];
        atomicAdd(loss_acc, t);
    }
}

__global__ void finalize_kernel(const float* __restrict__ loss_acc, float* __restrict__ out_loss,
                                float invN) {
    if (threadIdx.x == 0 && blockIdx.x == 0) out_loss[0] = loss_acc[0] * invN;
}

extern "C" void kernel_launch(void* const* d_in, const int* in_sizes, int n_in,
                              void* d_out, int out_size, void* d_ws, size_t ws_size,
                              hipStream_t stream) {
    const float* feats  = (const float*)d_in[0];
    const float* y_s    = (const float*)d_in[1];
    const float* cov_in = (const float*)d_in[2];
    const float* Ave_in = (const float*)d_in[3];
    const float* Amount = (const float*)d_in[4];
    const int*   labels = (const int*)d_in[5];

    const int C = in_sizes[4];
    const int N = in_sizes[5];
    const int A = in_sizes[3] / C;

    float* out      = (float*)d_out;
    float* out_loss = out;
    float* out_cov  = out + 1;
    float* out_ave  = out_cov + (size_t)C * A * A;
    float* out_amt  = out_ave + (size_t)C * A;

    char* w8 = (char*)d_ws;
    int* offsets    = (int*)w8;   w8 += (size_t)(C + 1) * sizeof(int);
    int* cursors    = (int*)w8;   w8 += (size_t)C * sizeof(int);
    int* idx_sorted = (int*)w8;   w8 += (size_t)N * sizeof(int);
    float* loss_acc = (float*)w8; w8 += sizeof(float);
    float* w_arr    = (float*)w8; w8 += (size_t)C * sizeof(float);
    float* inv_cs   = (float*)w8; w8 += (size_t)C * sizeof(float);
    float* ave_new  = (float*)w8; w8 += (size_t)C * A * sizeof(float);

    fused_prep<<<1, 1024, 0, stream>>>(labels, Amount, offsets, cursors, w_arr, inv_cs,
                                       out_amt, loss_acc, N, C);
    scatter_kernel<<<(N + 255) / 256, 256, 0, stream>>>(labels, offsets, cursors, idx_sorted, N);
    ave_kernel<<<dim3(A / 128, C), 128, 0, stream>>>(feats, Ave_in, idx_sorted, offsets,
                                                     w_arr, inv_cs, ave_new, out_ave, A);
    dim3 grid(A / TM, A / TM, C);
    cov_kernel<<<grid, 256, 0, stream>>>(feats, cov_in, ave_new, Ave_in, idx_sorted, offsets,
                                         w_arr, inv_cs, out_cov, A);
    loss_kernel<<<64, 256, 0, stream>>>(y_s, labels, loss_acc, N, C);
    finalize_kernel<<<1, 64, 0, stream>>>(loss_acc, out_loss, 1.f / (float)N);
}